// Round 2
// baseline (344.415 us; speedup 1.0000x reference)
//
#include <hip/hip_runtime.h>

#define NN 50000
#define NE 800000
#define TRF 64   // rows per tile in the fused kernel (8 rows per thread)

// ---------------------------------------------------------------------------
// Algebraic reduction (verified): softmax weights per (node,head) sum to 1, so
//   agg[n] = v[n] * (indegree(n)>0), and
//   out_row = LN(nodes + bo + mask * (nodes @ (Wv@Wo) + bv@Wo)).
// ws layout: Wc[128*128] floats | bc[128] floats | mask[NN] ints
// LDS budget: Wl 32KB + Ndl 32KB = 65536 B exactly (<= 64 KiB limit; the
// round-0 version was 65792 B, the prime suspect for the launch abort).
// ---------------------------------------------------------------------------

__device__ __forceinline__ void async_copy16(void* lds_dst, const void* gsrc) {
    __builtin_amdgcn_global_load_lds(
        (const __attribute__((address_space(1))) void*)gsrc,
        (__attribute__((address_space(3))) void*)lds_dst,
        16, 0, 0);
}

// Kernel A: zero the indegree mask (must precede the scatter of 1s).
__global__ __launch_bounds__(256) void init_mask_kernel(int* __restrict__ mask)
{
    int i = blockIdx.x * 256 + threadIdx.x;   // int4 index; NN % 4 == 0
    if (i < NN / 4) ((int4*)mask)[i] = make_int4(0, 0, 0, 0);
}

// Kernel B: Wc = Wv@Wo and bc = bv@Wo (blocks 0..64) run CONCURRENTLY with
// the edge scatter (blocks 65..) — they are independent.
__global__ __launch_bounds__(256) void prep_scatter_kernel(
    const float* __restrict__ Wv, const float* __restrict__ bv,
    const float* __restrict__ Wo, const int* __restrict__ tgt,
    float* __restrict__ Wc, float* __restrict__ bc, int* __restrict__ mask)
{
    int b = blockIdx.x, t = threadIdx.x;
    if (b < 64) {
        int k = 2 * b + (t >> 7);
        int j = t & 127;
        float acc = 0.f;
        #pragma unroll 4
        for (int m = 0; m < 128; ++m)
            acc = fmaf(Wv[k * 128 + m], Wo[m * 128 + j], acc);
        Wc[k * 128 + j] = acc;
    } else if (b == 64) {
        if (t < 128) {
            float acc = 0.f;
            #pragma unroll 4
            for (int m = 0; m < 128; ++m)
                acc = fmaf(bv[m], Wo[m * 128 + t], acc);
            bc[t] = acc;
        }
    } else {
        int i = (b - 65) * 256 + t;          // int4 index; NE % 4 == 0
        if (i < NE / 4) {
            int4 e = ((const int4*)tgt)[i];
            // benign race: all writers store 1
            mask[e.x] = 1; mask[e.y] = 1; mask[e.z] = 1; mask[e.w] = 1;
        }
    }
}

// Kernel C: out = LN(nodes + bo + mask*(nodes@Wc + bc)).
// 64-row tiles, 8 rows x 4 cols per thread: cuts per-row W-fragment LDS reads
// vs the 4-row version (LDS issue was the binding pipe). Staging via
// global_load_lds: LDS dest is wave-linear (base + lane*16), global src
// per-lane — the legal layout. Source rows clamped so NO wave ever issues
// global_load_lds under a partial exec mask.
__global__ __launch_bounds__(256, 2) void fused_kernel(
    const float* __restrict__ nodes,
    const float* __restrict__ Wc, const float* __restrict__ bc,
    const int* __restrict__ mask,
    const float* __restrict__ bo,
    const float* __restrict__ gamma, const float* __restrict__ beta,
    float* __restrict__ out)
{
    __shared__ float Wl[64 * 128];    // 32 KB: one K-half of W_comb
    __shared__ float Ndl[TRF * 128];  // 32 KB: node tile

    const int tid   = threadIdx.x;
    const int cg    = tid & 31;       // column group: cols 4*cg .. 4*cg+3
    const int slot  = tid >> 5;       // 0..7, rows slot*8 .. slot*8+7
    const int rbase = slot * 8;
    const int r0    = blockIdx.x * TRF;

    // stage node tile: 64 rows x 32 float4 = 2048 float4, 8 per thread.
    // Clamp OOB rows to NN-1: harmless duplicate data, never stored
    // (r < NN guard in epilogue; LN shuffles never cross rows).
    #pragma unroll
    for (int i = 0; i < 8; ++i) {
        int f  = tid + 256 * i;
        int gr = r0 + (f >> 5);
        if (gr > NN - 1) gr = NN - 1;
        async_copy16((float4*)Ndl + f, (const float4*)nodes + gr * 32 + (f & 31));
    }
    // stage W half 0
    #pragma unroll
    for (int i = 0; i < 8; ++i) {
        int f = tid + 256 * i;
        async_copy16((float4*)Wl + f, (const float4*)Wc + f);
    }
    // mask bits for this thread's 8 rows (register, not LDS; broadcast loads,
    // latency hidden under the GEMM)
    int mbits = 0;
    #pragma unroll
    for (int rr = 0; rr < 8; ++rr) {
        int r = r0 + rbase + rr;
        if (r < NN && mask[r]) mbits |= (1 << rr);
    }

    const float4 bo4 = ((const float4*)bo)[cg];
    const float4 bc4 = ((const float4*)bc)[cg];
    const float4 g4  = ((const float4*)gamma)[cg];
    const float4 be4 = ((const float4*)beta)[cg];

    float4 acc[8];
    #pragma unroll
    for (int rr = 0; rr < 8; ++rr) acc[rr] = make_float4(0.f, 0.f, 0.f, 0.f);

    __syncthreads();   // vmcnt drain: Ndl and Wl(h=0) ready

    #pragma unroll
    for (int h = 0; h < 2; ++h) {
        if (h) {
            __syncthreads();   // all reads of W half-0 done
            #pragma unroll
            for (int i = 0; i < 8; ++i) {
                int f = tid + 256 * i;
                async_copy16((float4*)Wl + f, (const float4*)(Wc + 64 * 128) + f);
            }
            __syncthreads();   // vmcnt drain: W half-1 ready
        }
        #pragma unroll 2
        for (int k4 = 0; k4 < 16; ++k4) {
            const float4* wr = (const float4*)(Wl + k4 * 4 * 128);
            float4 w0 = wr[cg];
            float4 w1 = wr[32 + cg];
            float4 w2 = wr[64 + cg];
            float4 w3 = wr[96 + cg];
            #pragma unroll
            for (int rr = 0; rr < 8; ++rr) {
                float4 nv = ((const float4*)(Ndl + (rbase + rr) * 128))[h * 16 + k4];
                acc[rr].x = fmaf(nv.x, w0.x, acc[rr].x);
                acc[rr].x = fmaf(nv.y, w1.x, acc[rr].x);
                acc[rr].x = fmaf(nv.z, w2.x, acc[rr].x);
                acc[rr].x = fmaf(nv.w, w3.x, acc[rr].x);
                acc[rr].y = fmaf(nv.x, w0.y, acc[rr].y);
                acc[rr].y = fmaf(nv.y, w1.y, acc[rr].y);
                acc[rr].y = fmaf(nv.z, w2.y, acc[rr].y);
                acc[rr].y = fmaf(nv.w, w3.y, acc[rr].y);
                acc[rr].z = fmaf(nv.x, w0.z, acc[rr].z);
                acc[rr].z = fmaf(nv.y, w1.z, acc[rr].z);
                acc[rr].z = fmaf(nv.z, w2.z, acc[rr].z);
                acc[rr].z = fmaf(nv.w, w3.z, acc[rr].z);
                acc[rr].w = fmaf(nv.x, w0.w, acc[rr].w);
                acc[rr].w = fmaf(nv.y, w1.w, acc[rr].w);
                acc[rr].w = fmaf(nv.z, w2.w, acc[rr].w);
                acc[rr].w = fmaf(nv.w, w3.w, acc[rr].w);
            }
        }
    }

    // epilogue: residual + bias + mask, LayerNorm across 128 cols
    #pragma unroll
    for (int rr = 0; rr < 8; ++rr) {
        int r = r0 + rbase + rr;
        float4 nd = ((const float4*)(Ndl + (rbase + rr) * 128))[cg];
        float m = ((mbits >> rr) & 1) ? 1.f : 0.f;
        float4 x;
        x.x = nd.x + bo4.x + m * (acc[rr].x + bc4.x);
        x.y = nd.y + bo4.y + m * (acc[rr].y + bc4.y);
        x.z = nd.z + bo4.z + m * (acc[rr].z + bc4.z);
        x.w = nd.w + bo4.w + m * (acc[rr].w + bc4.w);

        float s  = x.x + x.y + x.z + x.w;
        float ss = x.x * x.x + x.y * x.y + x.z * x.z + x.w * x.w;
        #pragma unroll
        for (int off = 1; off < 32; off <<= 1) {
            s  += __shfl_xor(s, off);
            ss += __shfl_xor(ss, off);
        }
        float mu   = s * (1.f / 128.f);
        float var  = ss * (1.f / 128.f) - mu * mu;
        float rstd = rsqrtf(var + 1e-5f);

        float4 o;
        o.x = (x.x - mu) * rstd * g4.x + be4.x;
        o.y = (x.y - mu) * rstd * g4.y + be4.y;
        o.z = (x.z - mu) * rstd * g4.z + be4.z;
        o.w = (x.w - mu) * rstd * g4.w + be4.w;
        if (r < NN) ((float4*)out)[r * 32 + cg] = o;
    }
}

extern "C" void kernel_launch(void* const* d_in, const int* in_sizes, int n_in,
                              void* d_out, int out_size, void* d_ws, size_t ws_size,
                              hipStream_t stream) {
    const float* nodes = (const float*)d_in[0];
    const int*   ei    = (const int*)d_in[2];
    const float* Wv    = (const float*)d_in[9];
    const float* bv    = (const float*)d_in[10];
    const float* Wo    = (const float*)d_in[21];
    const float* bo    = (const float*)d_in[22];
    const float* gamma = (const float*)d_in[23];
    const float* beta  = (const float*)d_in[24];

    float* Wc   = (float*)d_ws;          // 16384 floats
    float* bc   = Wc + 16384;            // 128 floats
    int*   mask = (int*)(bc + 128);      // NN ints

    init_mask_kernel<<<(NN / 4 + 255) / 256, 256, 0, stream>>>(mask);
    prep_scatter_kernel<<<65 + (NE / 4 + 255) / 256, 256, 0, stream>>>(
        Wv, bv, Wo, ei + NE, Wc, bc, mask);
    fused_kernel<<<(NN + TRF - 1) / TRF, 256, 0, stream>>>(
        nodes, Wc, bc, mask, bo, gamma, beta, (float*)d_out);
}

// Round 3
// 325.608 us; speedup vs baseline: 1.0578x; 1.0578x over previous
//
#include <hip/hip_runtime.h>

#define NN 50000
#define NE 800000

typedef __attribute__((ext_vector_type(8))) short short8;
typedef __attribute__((ext_vector_type(4))) float f32x4;

// ---------------------------------------------------------------------------
// Algebraic reduction (verified): softmax weights per (node,head) sum to 1, so
//   agg[n] = v[n] * (indegree(n)>0), and
//   out = LN(nodes + bo + mask * (nodes @ (Wv@Wo) + bv@Wo)).
// Round-2 post-mortem: the f32 vector-FMA GEMM is FMA-issue-bound (~25-30 us,
// irreducible on the VALU). This version moves the GEMM to bf16 MFMA with a
// 3-term Dekker split (error ~2^-16 rel, invisible vs absmax 0.0156).
// MFMA layouts (learn_hip-verified): A row=lane&15, k=8*(lane>>4)+e (contig 8);
// B col=lane&15, same k; D col=lane&15, row=4*(lane>>4)+reg.
// ws layout: Bhi[16384 u16] | Blo[16384 u16] | bc[128 f32] | mask[NN] int
// ---------------------------------------------------------------------------

__device__ __forceinline__ unsigned rne_bf16(float v) {
    unsigned u = __float_as_uint(v);
    return (u + 0x7FFFu + ((u >> 16) & 1u)) >> 16;
}

// Kernel A: zero the indegree mask.
__global__ __launch_bounds__(256) void init_mask_kernel(int* __restrict__ mask)
{
    int i = blockIdx.x * 256 + threadIdx.x;   // int4 index; NN % 4 == 0
    if (i < NN / 4) ((int4*)mask)[i] = make_int4(0, 0, 0, 0);
}

// Kernel B: blocks 0..63 compute Wc = Wv@Wo and pack bf16 hi/lo fragments in
// MFMA fragment-linear order; block 64 computes bc = bv@Wo; blocks 65+ scatter
// the indegree mask. All three parts independent -> run concurrently.
__global__ __launch_bounds__(256) void prep_scatter_kernel(
    const float* __restrict__ Wv, const float* __restrict__ bv,
    const float* __restrict__ Wo, const int* __restrict__ tgt,
    unsigned short* __restrict__ Bhi, unsigned short* __restrict__ Blo,
    float* __restrict__ bc, int* __restrict__ mask)
{
    int b = blockIdx.x, t = threadIdx.x;
    if (b < 64) {
        int k = 2 * b + (t >> 7);   // Wc row (K index)
        int n = t & 127;            // Wc col (N index)
        float acc = 0.f;
        #pragma unroll 4
        for (int m = 0; m < 128; ++m)
            acc = fmaf(Wv[k * 128 + m], Wo[m * 128 + n], acc);
        unsigned hb = rne_bf16(acc);
        float res = acc - __uint_as_float(hb << 16);
        unsigned lb = rne_bf16(res);
        // fragment-linear index: [kstep s][ntile][lane][e]
        int s = k >> 5, kk = k & 31, g = kk >> 3, e = kk & 7;
        int lane = (g << 4) | (n & 15), tn = n >> 4;
        int idx = (((s * 8 + tn) * 64) + lane) * 8 + e;
        Bhi[idx] = (unsigned short)hb;
        Blo[idx] = (unsigned short)lb;
    } else if (b == 64) {
        if (t < 128) {
            float acc = 0.f;
            #pragma unroll 4
            for (int m = 0; m < 128; ++m)
                acc = fmaf(bv[m], Wo[m * 128 + t], acc);
            bc[t] = acc;
        }
    } else {
        int i = (b - 65) * 256 + t;          // int4 index; NE % 4 == 0
        if (i < NE / 4) {
            int4 e = ((const int4*)tgt)[i];
            mask[e.x] = 1; mask[e.y] = 1; mask[e.z] = 1; mask[e.w] = 1;
        }
    }
}

// Kernel C: out = LN(nodes + bo + mask*(nodes@Wc + bc)) via split-bf16 MFMA.
// No LDS, no barriers: each wave owns 16 rows; A-frags straight from global,
// B-frags from the pre-packed fragment arrays (L2-resident, shared chip-wide).
__global__ __launch_bounds__(256, 4) void fused_kernel(
    const float* __restrict__ nodes,
    const unsigned short* __restrict__ Bhi, const unsigned short* __restrict__ Blo,
    const float* __restrict__ bc, const int* __restrict__ mask,
    const float* __restrict__ bo,
    const float* __restrict__ gamma, const float* __restrict__ beta,
    float* __restrict__ out)
{
    const int lane = threadIdx.x & 63;
    const int wv   = threadIdx.x >> 6;
    const int g    = lane >> 4;
    const int ln   = lane & 15;
    const int Rb   = blockIdx.x * 64 + wv * 16;   // wave's 16-row tile base

    int Ra = Rb + ln;                 // A-side row for this lane
    if (Ra > NN - 1) Ra = NN - 1;     // clamp: duplicate rows never stored
    const float4* arow = (const float4*)(nodes + (long)Ra * 128);

    f32x4 acc[8];
    #pragma unroll
    for (int t = 0; t < 8; ++t) { acc[t][0] = 0.f; acc[t][1] = 0.f; acc[t][2] = 0.f; acc[t][3] = 0.f; }

    #pragma unroll
    for (int s = 0; s < 4; ++s) {     // K-steps of 32
        // A fragment: 8 contiguous f32 at k = 32s + 8g (two float4)
        float4 a0 = arow[s * 8 + 2 * g];
        float4 a1 = arow[s * 8 + 2 * g + 1];
        float av[8] = {a0.x, a0.y, a0.z, a0.w, a1.x, a1.y, a1.z, a1.w};
        short8 ahi, alo;
        #pragma unroll
        for (int e = 0; e < 8; ++e) {
            unsigned u = __float_as_uint(av[e]);
            ahi[e] = (short)(u >> 16);                       // truncate-to-bf16
            float res = av[e] - __uint_as_float(u & 0xFFFF0000u);  // exact
            alo[e] = (short)(__float_as_uint(res) >> 16);
        }
        const short8* bh = (const short8*)(Bhi) + (s * 8) * 64;
        const short8* bl = (const short8*)(Blo) + (s * 8) * 64;
        #pragma unroll
        for (int t = 0; t < 8; ++t) {
            short8 bhv = bh[t * 64 + lane];
            short8 blv = bl[t * 64 + lane];
            acc[t] = __builtin_amdgcn_mfma_f32_16x16x32_bf16(ahi, bhv, acc[t], 0, 0, 0);
            acc[t] = __builtin_amdgcn_mfma_f32_16x16x32_bf16(ahi, blv, acc[t], 0, 0, 0);
            acc[t] = __builtin_amdgcn_mfma_f32_16x16x32_bf16(alo, bhv, acc[t], 0, 0, 0);
        }
    }

    // per-column parameters (col = 16t + ln), reused across the 4 output rows
    float bo8[8], bc8[8], gm8[8], bt8[8];
    #pragma unroll
    for (int t = 0; t < 8; ++t) {
        int c = 16 * t + ln;
        bo8[t] = bo[c]; bc8[t] = bc[c]; gm8[t] = gamma[c]; bt8[t] = beta[c];
    }

    // epilogue: D row = Rb + 4g + r, col = 16t + ln; LN across the 16-lane group
    #pragma unroll
    for (int r = 0; r < 4; ++r) {
        int Rd = Rb + 4 * g + r;
        int Rc = (Rd > NN - 1) ? NN - 1 : Rd;
        float m = (mask[Rc] != 0) ? 1.f : 0.f;
        const float* nrow = nodes + (long)Rc * 128;
        float x[8];
        float sum = 0.f, ssum = 0.f;
        #pragma unroll
        for (int t = 0; t < 8; ++t) {
            x[t] = nrow[16 * t + ln] + bo8[t] + m * (acc[t][r] + bc8[t]);
            sum  += x[t];
            ssum += x[t] * x[t];
        }
        #pragma unroll
        for (int off = 1; off < 16; off <<= 1) {   // reduce within 16-lane group
            sum  += __shfl_xor(sum, off);
            ssum += __shfl_xor(ssum, off);
        }
        float mu   = sum * (1.f / 128.f);
        float var  = ssum * (1.f / 128.f) - mu * mu;
        float rstd = rsqrtf(var + 1e-5f);
        if (Rd < NN) {
            float* orow = out + (long)Rd * 128;
            #pragma unroll
            for (int t = 0; t < 8; ++t)
                orow[16 * t + ln] = (x[t] - mu) * rstd * gm8[t] + bt8[t];
        }
    }
}

extern "C" void kernel_launch(void* const* d_in, const int* in_sizes, int n_in,
                              void* d_out, int out_size, void* d_ws, size_t ws_size,
                              hipStream_t stream) {
    const float* nodes = (const float*)d_in[0];
    const int*   ei    = (const int*)d_in[2];
    const float* Wv    = (const float*)d_in[9];
    const float* bv    = (const float*)d_in[10];
    const float* Wo    = (const float*)d_in[21];
    const float* bo    = (const float*)d_in[22];
    const float* gamma = (const float*)d_in[23];
    const float* beta  = (const float*)d_in[24];

    unsigned short* Bhi = (unsigned short*)d_ws;          // 16384 u16 = 32 KB
    unsigned short* Blo = Bhi + 16384;                    // 32 KB
    float*          bcp = (float*)(Blo + 16384);          // 128 f32
    int*            mask = (int*)(bcp + 128);             // NN ints (16B-aligned)

    init_mask_kernel<<<(NN / 4 + 255) / 256, 256, 0, stream>>>(mask);
    prep_scatter_kernel<<<65 + (NE / 4 + 255) / 256, 256, 0, stream>>>(
        Wv, bv, Wo, ei + NE, Bhi, Blo, bcp, mask);
    fused_kernel<<<(NN + 63) / 64, 256, 0, stream>>>(
        nodes, Bhi, Blo, bcp, mask, bo, gamma, beta, (float*)d_out);
}